// Round 9
// baseline (148.698 us; speedup 1.0000x reference)
//
#include <hip/hip_runtime.h>
#include <hip/hip_bf16.h>

// IRChannelAttention on MI355X. Round 25: 2x2 PV wave tiling + setprio.
// r24 (no-vmcnt-drain barrier) was neutral -> the stall is LDS-pipe
// occupancy, not the barrier drain. Biggest LDS term: PV's 1x4 tiling
// makes each wave read ALL 4 V c-tiles (8 b128) while A costs 2 -> 10
// reads/wave/kt. 2x2 tiling (wave = 32c x 32n quadrant): A = 2 n-strips
// (4 reads) + B = 2 c-tiles (4 reads) = 8 reads, same 8 MFMA, same accO
// regs -- addressing-only change. Plus T5 s_setprio(1) around MFMA
// clusters (+4-7% measured on attn structures). Skeleton unchanged.
// B=2, C=64, H=W=80, N=6400. fp32 global I/O, bf16 ws intermediates.

#define BATCH 2
#define CH 64
#define HH 80
#define WW 80
#define NN 6400
#define NT 100          // NN / 64
#define KS 5            // key splits (divides NT)
#define KTPS (NT/KS)    // 20 key tiles per split
#define EPSV 1e-5f
#define NEGBIG (-1e30f)
#define LOG2E8 0.18033688f   // log2(e)/8, folded into Q weights

typedef __hip_bfloat16 bf16;
typedef __attribute__((ext_vector_type(8))) short short8;   // MFMA A/B frag
typedef __attribute__((ext_vector_type(4))) float f4;       // MFMA C/D frag
#define MFMA16 __builtin_amdgcn_mfma_f32_16x16x32_bf16

__device__ __forceinline__ float b2f(bf16 v){ return __bfloat162float(v); }
__device__ __forceinline__ bf16 f2b(float v){ return __float2bfloat16(v); }
__device__ __forceinline__ ushort f2bu(float v){ return ((__hip_bfloat16_raw)__float2bfloat16(v)).x; }
__device__ __forceinline__ float bu2f(ushort u){
  union { unsigned int i; float f; } w; w.i = ((unsigned int)u) << 16; return w.f;
}
__device__ __forceinline__ unsigned pkbf(float a, float b){   // packed bf16x2
  union { __hip_bfloat162 h2; unsigned u; } cv;
  cv.h2 = __float22bfloat162_rn(make_float2(a, b));
  return cv.u;
}
__device__ __forceinline__ float fexp2(float x){
#if __has_builtin(__builtin_amdgcn_exp2f)
  return __builtin_amdgcn_exp2f(x);
#else
  return exp2f(x);
#endif
}
// byte offset into a [64][64] bf16 tile (128B rows), st-16x32 XOR swizzle.
__device__ __forceinline__ int swz(int row, int colb){
  return row*128 + (colb ^ ((row & 7) << 4));
}
// LDS-only barrier: order my ds ops, sync waves, do NOT drain vmcnt.
// Memory clobbers + sched_barrier(0) (rule #18) pin LDS ops to their side.
__device__ __forceinline__ void sync_lds_only(){
  asm volatile("s_waitcnt lgkmcnt(0)" ::: "memory");
  __builtin_amdgcn_s_barrier();
  __builtin_amdgcn_sched_barrier(0);
  asm volatile("" ::: "memory");
}

// ws layout (bytes)
#define OFF_BIAS 0                              // 192 fp32: BQ(scaled) BK BVP
#define OFF_WH_B 768                            // 4 x 4096 bf16: wq | wvp | wa1 | wa2m  ([co][ci])
#define OFF_LOW_B (768 + 32768)                 // lowg bf16 [b][c][n]
#define OFF_Q_B   (OFF_LOW_B + BATCH*CH*NN*2)   // qgT bf16 [b][n][c]
#define OFF_K_B   (OFF_Q_B   + BATCH*CH*NN*2)   // kgT bf16 [b][n][c]
#define OFF_V_B   (OFF_K_B   + BATCH*CH*NN*2)   // vgc (=V') bf16 [b][c][n]
#define OFF_P_B   (OFF_V_B   + BATCH*CH*NN*2)   // part bf16 [(b*NT+t)*KS+s][c][n]
#define OFF_ML_B  (OFF_P_B   + BATCH*NT*KS*4096*2) // l fp32 [(b*NT+t)*KS+s][64]
// total ~15.3 MB

// grid 16 x 256: one (ci,co) per thread; lane -> ci. Weights staged to LDS.
// Folds: wq (+BN+softmax scale), wa1/wa2m (K chain), wvp = Wo @ (vw*bnscale).
// Storage layout [co][ci] (ci lane-fast -> contiguous writes).
__global__ __launch_bounds__(256) void setup_fold(
    const float* __restrict__ q1w, const float* __restrict__ q1g, const float* __restrict__ q1b,
    const float* __restrict__ q2w, const float* __restrict__ q2g, const float* __restrict__ q2b,
    const float* __restrict__ q3w, const float* __restrict__ q3g, const float* __restrict__ q3b,
    const float* __restrict__ khw, const float* __restrict__ khb,
    const float* __restrict__ klw, const float* __restrict__ klb,
    const float* __restrict__ kfw, const float* __restrict__ kfb,
    const float* __restrict__ vg,  const float* __restrict__ vbnb,
    const float* __restrict__ vw,  const float* __restrict__ vb,
    const float* __restrict__ outw,
    float* __restrict__ biasf, bf16* __restrict__ wh)
{
  __shared__ __align__(16) float skf[4096];   // kfw  [co][64]
  __shared__ __align__(16) float skh[2048];   // khw  [j][64ci]
  __shared__ __align__(16) float skl[2048];   // klw  [j][64ci]
  __shared__ __align__(16) float sow[4096];   // outw [co][64]
  __shared__ __align__(16) float svw[4096];   // vw   [j][64ci]
  __shared__ float sbv[64];                   // bv_old[j] = vb + vw@vbnb

  int tid = threadIdx.x;
  int blk = blockIdx.x;
  #pragma unroll
  for (int i = 0; i < 4; ++i) {
    *(float4*)&skf[(i*256 + tid)*4] = *(const float4*)&kfw[(i*256 + tid)*4];
    *(float4*)&sow[(i*256 + tid)*4] = *(const float4*)&outw[(i*256 + tid)*4];
    *(float4*)&svw[(i*256 + tid)*4] = *(const float4*)&vw[(i*256 + tid)*4];
  }
  #pragma unroll
  for (int i = 0; i < 2; ++i) {
    *(float4*)&skh[(i*256 + tid)*4] = *(const float4*)&khw[(i*256 + tid)*4];
    *(float4*)&skl[(i*256 + tid)*4] = *(const float4*)&klw[(i*256 + tid)*4];
  }
  __syncthreads();

  float rs = rsqrtf(1.0f + EPSV);
  if (tid < 64) {
    int j = tid;
    float bvo = vb[j];
    for (int ci2 = 0; ci2 < 64; ++ci2) bvo += svw[j*64 + ci2] * vbnb[ci2];
    sbv[j] = bvo;
  }

  bf16* wq   = wh;
  bf16* wvp  = wh + 4096;
  bf16* wa1  = wh + 8192;
  bf16* wa2m = wh + 12288;

  int t = blk*256 + tid;
  int ci = t & 63, co = t >> 6;        // ci = lane-fast
  int o = co*64 + ci;                  // [co][ci] storage (ci contiguous)

  float w = 0.f, g;
  if (co < 21)      { g = q1g[co];    w = (ci < 21)              ? q1w[co*21 + ci]            : 0.f; }
  else if (co < 42) { g = q2g[co-21]; w = (ci >= 21 && ci < 42)  ? q2w[(co-21)*21 + (ci-21)]  : 0.f; }
  else              { g = q3g[co-42]; w = (ci >= 42)             ? q3w[(co-42)*22 + (ci-42)]  : 0.f; }
  wq[o] = f2b(w * g * rs * LOG2E8);

  float a1 = 0.f, a2 = 0.f;
  #pragma unroll
  for (int j = 0; j < 32; ++j) {
    a1 += skf[co*64 + j]      * skh[j*64 + ci];
    a2 += skf[co*64 + 32 + j] * skl[j*64 + ci];
  }
  wa1[o]  = f2b(a1);
  wa2m[o] = f2b(a2 - a1);              // K = A1@x + (A2-A1)@low + bK

  // V' weight: wvp[co][ci] = rs*vg[ci] * sum_j outw[co][j]*vw[j][ci]
  float av = 0.f;
  #pragma unroll
  for (int j = 0; j < 64; ++j)
    av += sow[co*64 + j] * svw[j*64 + ci];
  wvp[o] = f2b(av * vg[ci] * rs);

  if (blk == 0 && tid < 64) {
    int c2 = tid;
    float bq;
    if (c2 < 21)      bq = q1b[c2];
    else if (c2 < 42) bq = q2b[c2-21];
    else              bq = q3b[c2-42];
    biasf[c2] = bq * LOG2E8;
    float bk = kfb[c2];
    #pragma unroll
    for (int j = 0; j < 32; ++j) {
      bk += skf[c2*64 + j]      * khb[j];
      bk += skf[c2*64 + 32 + j] * klb[j];
    }
    biasf[64 + c2] = bk;
    float bvp = 0.f;
    #pragma unroll
    for (int j = 0; j < 64; ++j) bvp += sow[c2*64 + j] * sbv[j];
    biasf[128 + c2] = bvp;
  }
}

// 4 outputs/thread, aligned float4 sliding windows. grid 800.
__global__ __launch_bounds__(256) void pool_low(const float* __restrict__ x,
                                                bf16* __restrict__ lowg)
{
  int t4 = (blockIdx.x*256 + threadIdx.x)*4;
  int bc = t4 / NN; int n = t4 % NN;
  int h = n / WW, w0 = n % WW;                 // w0 multiple of 4
  const float* p = x + bc*NN;
  float m5[4], m3[4];
  #pragma unroll
  for (int j=0;j<4;++j){ m5[j]=NEGBIG; m3[j]=NEGBIG; }
  #pragma unroll
  for (int dh = -2; dh <= 2; ++dh) {
    int hh = h + dh; if (hh < 0 || hh >= HH) continue;
    float r[12];
    const float* row = p + hh*WW;
    if (w0 >= 4)      { float4 a = *(const float4*)&row[w0-4]; r[0]=a.x;r[1]=a.y;r[2]=a.z;r[3]=a.w; }
    else              { r[0]=NEGBIG;r[1]=NEGBIG;r[2]=NEGBIG;r[3]=NEGBIG; }
    { float4 a = *(const float4*)&row[w0]; r[4]=a.x;r[5]=a.y;r[6]=a.z;r[7]=a.w; }
    if (w0 + 7 < WW)  { float4 a = *(const float4*)&row[w0+4]; r[8]=a.x;r[9]=a.y;r[10]=a.z;r[11]=a.w; }
    else              { r[8]=NEGBIG;r[9]=NEGBIG;r[10]=NEGBIG;r[11]=NEGBIG; }
    bool in3 = (dh >= -1 && dh <= 1);
    #pragma unroll
    for (int j=0;j<4;++j) {
      float v3 = fmaxf(fmaxf(r[3+j], r[4+j]), r[5+j]);
      float v5 = fmaxf(fmaxf(r[2+j], v3), r[6+j]);
      m5[j] = fmaxf(m5[j], v5);
      if (in3) m3[j] = fmaxf(m3[j], v3);
    }
  }
  ushort4 o;
  o.x = f2bu(0.5f*(m3[0]+m5[0]));
  o.y = f2bu(0.5f*(m3[1]+m5[1]));
  o.z = f2bu(0.5f*(m3[2]+m5[2]));
  o.w = f2bu(0.5f*(m3[3]+m5[3]));
  *(ushort4*)&lowg[t4] = o;
}

// ---------------------------------------------------------------------------
// qkv_kernel (MFMA): one 64-n tile per block, grid B*NT = 200, 4 waves.
// Stage x(f32->bf16) and low transposed into LDS [n][ci] (swizzled).
// Weights direct-from-global ([co][ci], 16B frags). 32 MFMA/wave.
// ---------------------------------------------------------------------------
__global__ __launch_bounds__(256, 2) void qkv_kernel(
    const float* __restrict__ x, const float* __restrict__ biasf,
    const bf16* __restrict__ wh, const bf16* __restrict__ lowg,
    bf16* __restrict__ qgT, bf16* __restrict__ kgT, bf16* __restrict__ vgc)
{
  __shared__ __align__(16) char xT[8192];   // [64n][64ci] bf16, swizzled
  __shared__ __align__(16) char lT[8192];
  __shared__ float bias[192];

  int tid = threadIdx.x;
  int blk = blockIdx.x;
  int b = blk / NT, tile = blk % NT;
  int n0 = tile*64;
  int wv = tid >> 6, lane = tid & 63, ln = lane & 15, quad = lane >> 4;

  if (tid < 192) bias[tid] = biasf[tid];

  // ---- transpose-stage: thread owns 4c x 4n (c=cq*4, n=nq*4) ----
  {
    int cq = tid & 15, nq = tid >> 4;
    const float* xp = x + (size_t)(b*CH + cq*4)*NN + n0 + nq*4;
    float4 x0 = *(const float4*)&xp[0*NN];
    float4 x1 = *(const float4*)&xp[(size_t)1*NN];
    float4 x2 = *(const float4*)&xp[(size_t)2*NN];
    float4 x3 = *(const float4*)&xp[(size_t)3*NN];
    const bf16* lp = lowg + (size_t)(b*CH + cq*4)*NN + n0 + nq*4;
    uint2 l0 = *(const uint2*)&lp[0*NN];
    uint2 l1 = *(const uint2*)&lp[(size_t)1*NN];
    uint2 l2 = *(const uint2*)&lp[(size_t)2*NN];
    uint2 l3 = *(const uint2*)&lp[(size_t)3*NN];
    uint2 w;
    // j = 0
    w.x = pkbf(x0.x, x1.x); w.y = pkbf(x2.x, x3.x);
    *(uint2*)(xT + swz(nq*4+0, cq*8)) = w;
    w.x = (l0.x & 0xffffu) | ((l1.x & 0xffffu) << 16);
    w.y = (l2.x & 0xffffu) | ((l3.x & 0xffffu) << 16);
    *(uint2*)(lT + swz(nq*4+0, cq*8)) = w;
    // j = 1
    w.x = pkbf(x0.y, x1.y); w.y = pkbf(x2.y, x3.y);
    *(uint2*)(xT + swz(nq*4+1, cq*8)) = w;
    w.x = (l0.x >> 16) | ((l1.x >> 16) << 16);
    w.y = (l2.x >> 16) | ((l3.x >> 16) << 16);
    *(uint2*)(lT + swz(nq*4+1, cq*8)) = w;
    // j = 2
    w.x = pkbf(x0.z, x1.z); w.y = pkbf(x2.z, x3.z);
    *(uint2*)(xT + swz(nq*4+2, cq*8)) = w;
    w.x = (l0.y & 0xffffu) | ((l1.y & 0xffffu) << 16);
    w.y = (l2.y & 0xffffu) | ((l3.y & 0xffffu) << 16);
    *(uint2*)(lT + swz(nq*4+2, cq*8)) = w;
    // j = 3
    w.x = pkbf(x0.w, x1.w); w.y = pkbf(x2.w, x3.w);
    *(uint2*)(xT + swz(nq*4+3, cq*8)) = w;
    w.x = (l0.y >> 16) | ((l1.y >> 16) << 16);
    w.y = (l2.y >> 16) | ((l3.y >> 16) << 16);
    *(uint2*)(lT + swz(nq*4+3, cq*8)) = w;
  }
  __syncthreads();

  // ---- xT B-frags (cols n = nt*16+ln), named ----
  short8 xb00 = *(const short8*)(xT + swz(0*16 + ln, quad*16));
  short8 xb01 = *(const short8*)(xT + swz(0*16 + ln, 64 + quad*16));
  short8 xb10 = *(const short8*)(xT + swz(1*16 + ln, quad*16));
  short8 xb11 = *(const short8*)(xT + swz(1*16 + ln, 64 + quad*16));
  short8 xb20 = *(const short8*)(xT + swz(2*16 + ln, quad*16));
  short8 xb21 = *(const short8*)(xT + swz(2*16 + ln, 64 + quad*16));
  short8 xb30 = *(const short8*)(xT + swz(3*16 + ln, quad*16));
  short8 xb31 = *(const short8*)(xT + swz(3*16 + ln, 64 + quad*16));
  // V' A-frags: rows n = wv*16+ln (dup load, avoids runtime-indexed select)
  short8 xa0 = *(const short8*)(xT + swz(wv*16 + ln, quad*16));
  short8 xa1 = *(const short8*)(xT + swz(wv*16 + ln, 64 + quad*16));

  int cb = wv*16 + quad*4;             // first of 4 output rows (Q/K) / n (V')
  const bf16* wqp  = wh;               // [co][ci]
  const bf16* wvpp = wh + 4096;
  const bf16* wa1p = wh + 8192;
  const bf16* wa2p = wh + 12288;
  int wrow = (wv*16 + ln)*64;

  // ================= V' : D[n][co] =================
  {
    {
      short8 w0 = *(const short8*)&wvpp[(0*16 + ln)*64 + quad*8];
      short8 w1 = *(const short8*)&wvpp[(0*16 + ln)*64 + 32 + quad*8];
      float bv = bias[128 + 0*16 + ln];
      f4 a = (f4){bv, bv, bv, bv};
      a = MFMA16(xa0, w0, a, 0, 0, 0);
      a = MFMA16(xa1, w1, a, 0, 0, 0);
      uint2 pk; pk.x = pkbf(a[0], a[1]); pk.y = pkbf(a[2], a[3]);
      *(uint2*)&vgc[(size_t)(b*CH + 0*16 + ln)*NN + n0 + cb] = pk;
    }
    {
      short8 w0 = *(const short8*)&wvpp[(1*16 + ln)*64 + quad*8];
      short8 w1 = *(const short8*)&wvpp[(1*16 + ln)*64 + 32 + quad*8];
      float bv = bias[128 + 1*16 + ln];
      f4 a = (f4){bv, bv, bv, bv};
      a = MFMA16(xa0, w0, a, 0, 0, 0);
      a = MFMA16(xa1, w1, a, 0, 0, 0);
      uint2 pk; pk.x = pkbf(a[0], a[1]); pk.y = pkbf(a[2], a[3]);
      *(uint2*)&vgc[(size_t)(b*CH + 1*16 + ln)*NN + n0 + cb] = pk;
    }
    {
      short8 w0 = *(const short8*)&wvpp[(2*16 + ln)*64 + quad*8];
      short8 w1 = *(const short8*)&wvpp[(2*16 + ln)*64 + 32 + quad*8];
      float bv = bias[128 + 2*16 + ln];
      f4 a = (f4){bv, bv, bv, bv};
      a = MFMA16(xa0, w0, a, 0, 0, 0);
      a = MFMA16(xa1, w1, a, 0, 0, 0);
      uint2 pk; pk.x = pkbf(a[0], a[1]); pk.y = pkbf(a[2], a[3]);
      *(uint2*)&vgc[(size_t)(b*CH + 2*16 + ln)*NN + n0 + cb] = pk;
    }
    {
      short8 w0 = *(const short8*)&wvpp[(3*16 + ln)*64 + quad*8];
      short8 w1 = *(const short8*)&wvpp[(3*16 + ln)*64 + 32 + quad*8];
      float bv = bias[128 + 3*16 + ln];
      f4 a = (f4){bv, bv, bv, bv};
      a = MFMA16(xa0, w0, a, 0, 0, 0);
      a = MFMA16(xa1, w1, a, 0, 0, 0);
      uint2 pk; pk.x = pkbf(a[0], a[1]); pk.y = pkbf(a[2], a[3]);
      *(uint2*)&vgc[(size_t)(b*CH + 3*16 + ln)*NN + n0 + cb] = pk;
    }
  }

  // ================= Q : D[co][n], ReLU =================
  {
    short8 wq0 = *(const short8*)&wqp[wrow + quad*8];
    short8 wq1 = *(const short8*)&wqp[wrow + 32 + quad*8];
    f4 bQ;
    bQ[0] = bias[cb+0]; bQ[1] = bias[cb+1]; bQ[2] = bias[cb+2]; bQ[3] = bias[cb+3];
    {
      f4 a = bQ;
      a = MFMA16(wq0, xb00, a, 0, 0, 0);
      a = MFMA16(wq1, xb01, a, 0, 0, 0);
      uint2 pk;
      pk.x = pkbf(fmaxf(a[0],0.f), fmaxf(a[1],0.f));
      pk.y = pkbf(fmaxf(a[2],0.f), fmaxf(a[3],0.f));
      *(uint2*)&qgT[(size_t)(b*NN + n0 + 0*16 + ln)*64 + cb] = pk;
    }
    {
      f4 a = bQ;
      a = MFMA16(wq0, xb10, a, 0, 0, 0);
      a = MFMA16(wq1, xb11, a, 0, 0, 0);
      uint2 pk;
      pk.x = pkbf(fmaxf(a[0],0.f), fmaxf(a[1],0.f));
      pk.y = pkbf(fmaxf(a[2],0.f), fmaxf(a[3],0.f));
      *(uint2*)&qgT[(size_t)(b*NN + n0 + 1*16 + ln)*64 + cb] = pk;
    }
    {
      f4 a = bQ;
      a = MFMA16(wq0, xb20, a, 0, 0, 0);
      a = MFMA16(wq1, xb21, a, 0, 0, 0);
      uint2 pk;
      pk.x = pkbf(fmaxf(a[0],0.f), fmaxf(a[1],0.f));
      pk.y = pkbf(fmaxf(a[2],0.f), fmaxf(a[3],0.f));
      *(uint2*)&qgT[(size_t)(b*NN + n0 + 2*16 + ln)*64 + cb] = pk;
    }
    {
      f4 a = bQ;
      a = MFMA16(wq0, xb30, a, 0, 0, 0);
      a = MFMA16(wq1, xb31, a, 0, 0, 0);
      uint2 pk;
      pk.x = pkbf(fmaxf(a[0],0.f), fmaxf(a[1],0.f));
      pk.y = pkbf(fmaxf(a[2],0.f), fmaxf(a[3],0.f));
      *(uint2*)&qgT[(size_t)(b*NN + n0 + 3*16 + ln)*64 + cb] = pk;
    }
  }

  // ================= K : D[co][n] = A1@x + (A2-A1)@low + bK =================
  {
    short8 wa10 = *(const short8*)&wa1p[wrow + quad*8];
    short8 wa11 = *(const short8*)&wa1p[wrow + 32 + quad*8];
    short8 wm0  = *(const short8*)&wa2p[wrow + quad*8];
    short8 wm1  = *(const short8*)&wa2p[wrow + 32 + quad*8];
    short8 lb00 = *(const short8*)(lT + swz(0*16 + ln, quad*16));
    short8 lb01 = *(const short8*)(lT + swz(0*16 + ln, 64 + quad*16));
    short8 lb10 = *(const short8*)(lT + swz(1*16 + ln, quad*16));
    short8 lb11 = *(const short8*)(lT + swz(1*16 + ln, 64 + quad*16));
    short8 lb20 = *(const short8*)(lT + swz(2*16 + ln, quad*16));
    short8 lb21 = *(const short8*)(lT + swz(2*16 + ln, 64 + quad*16));
    short8 lb30 = *(const short8*)(lT + swz(3*16 + ln, quad*16));
    short8 lb31 = *(const short8*)(lT + swz(3*16 + ln, 64 + quad*16));
    f4 bK;
    bK[0] = bias[64+cb+0]; bK[1] = bias[64+cb+1];
    bK[2] = bias[64+cb+2]; bK[3] = bias[64+cb+3];
    {
      f4 a = bK;
      a = MFMA16(wa10, xb00, a, 0, 0, 0);
      a = MFMA16(wa11, xb01, a, 0, 0, 0);
      a = MFMA16(wm0,  lb00, a, 0, 0, 0);
      a = MFMA16(wm1,  lb01, a, 0, 0, 0);
      uint2 pk; pk.x = pkbf(a[0], a[1]); pk.y = pkbf(a[2], a[3]);
      *(uint2*)&kgT[(size_t)(b*NN + n0 + 0*16 + ln)*64 + cb] = pk;
    }
    {
      f4 a = bK;
      a = MFMA16(wa10, xb10, a, 0, 0, 0);
      a = MFMA16(wa11, xb11, a, 0, 0, 0);
      a = MFMA16(wm0,  lb10, a, 0, 0, 0);
      a = MFMA16(wm1,  lb11, a, 0, 0, 0);
      uint2 pk; pk.x = pkbf(a[0], a[1]); pk.y = pkbf(a[2], a[3]);
      *(uint2*)&kgT[(size_t)(b*NN + n0 + 1*16 + ln)*64 + cb] = pk;
    }
    {
      f4 a = bK;
      a = MFMA16(wa10, xb20, a, 0, 0, 0);
      a = MFMA16(wa11, xb21, a, 0, 0, 0);
      a = MFMA16(wm0,  lb20, a, 0, 0, 0);
      a = MFMA16(wm1,  lb21, a, 0, 0, 0);
      uint2 pk; pk.x = pkbf(a[0], a[1]); pk.y = pkbf(a[2], a[3]);
      *(uint2*)&kgT[(size_t)(b*NN + n0 + 2*16 + ln)*64 + cb] = pk;
    }
    {
      f4 a = bK;
      a = MFMA16(wa10, xb30, a, 0, 0, 0);
      a = MFMA16(wa11, xb31, a, 0, 0, 0);
      a = MFMA16(wm0,  lb30, a, 0, 0, 0);
      a = MFMA16(wm1,  lb31, a, 0, 0, 0);
      uint2 pk; pk.x = pkbf(a[0], a[1]); pk.y = pkbf(a[2], a[3]);
      *(uint2*)&kgT[(size_t)(b*NN + n0 + 3*16 + ln)*64 + cb] = pk;
    }
  }
}

// ---------------------------------------------------------------------------
// attn_partial: split-K flash (r22/r24 skeleton). S^T = K.Q^T: A = K rows
// (direct global from kgT [n][c]); B = Q hoisted (8 named short8). V
// cooperatively staged to LDS with one-tile-ahead register prefetch; P/V
// double buffers [64][64] bf16 pitch 64 + XOR swizzle. ONE LDS-only barrier
// per kt. PV uses 2x2 wave tiling (wave = 32c x 32n quadrant): 8 LDS reads
// per wave per kt (was 10). s_setprio(1) around both MFMA clusters (T5).
// ---------------------------------------------------------------------------
__global__ __launch_bounds__(256, 2) void attn_partial(
    const bf16* __restrict__ qgT, const bf16* __restrict__ kgT, const bf16* __restrict__ vgc,
    ushort* __restrict__ part, float* __restrict__ pml)
{
  // [0,8192)=P0 (aliases Q stage), [8192,16384)=P1, [16384,24576)=V0,
  // [24576,32768)=V1
  __shared__ __align__(16) char smem[32768];
  __shared__ float lred[256];

  int tid = threadIdx.x;
  int blk = blockIdx.x;
  int b = blk / (NT*KS);
  int rem = blk % (NT*KS);
  int tile = rem / KS, split = rem % KS;
  int n0 = tile*64;
  int wv = tid >> 6, lane = tid & 63, ln = lane & 15, quad = lane >> 4;
  int cw = wv >> 1, nw = wv & 1;       // PV 2x2 quadrant coords
  int mbase = split*KTPS*64;

  // staging geometry (shared by Q/V stages): two 16B chunks per thread
  int r0 = tid >> 3,         c0 = (tid & 7)*8;        // chunk 0: rows 0..31
  int r1 = 32 + (tid >> 3),  c1 = (tid & 7)*8;        // chunk 1: rows 32..63

  // ---- stage Q [n][c] (swizzled), hoist ALL Q as 8 named B-frags ----
  {
    uint4 qa = *(const uint4*)&qgT[(size_t)(b*NN + n0 + r0)*64 + c0];
    uint4 qb = *(const uint4*)&qgT[(size_t)(b*NN + n0 + r1)*64 + c1];
    *(uint4*)(smem + swz(r0, c0*2)) = qa;
    *(uint4*)(smem + swz(r1, c1*2)) = qb;
  }
  __syncthreads();
  short8 bq00 = *(const short8*)(smem + swz( 0*16 + ln, quad*16));
  short8 bq01 = *(const short8*)(smem + swz( 0*16 + ln, 64 + quad*16));
  short8 bq10 = *(const short8*)(smem + swz( 1*16 + ln, quad*16));
  short8 bq11 = *(const short8*)(smem + swz( 1*16 + ln, 64 + quad*16));
  short8 bq20 = *(const short8*)(smem + swz( 2*16 + ln, quad*16));
  short8 bq21 = *(const short8*)(smem + swz( 2*16 + ln, 64 + quad*16));
  short8 bq30 = *(const short8*)(smem + swz( 3*16 + ln, quad*16));
  short8 bq31 = *(const short8*)(smem + swz( 3*16 + ln, 64 + quad*16));
  // stage V tile 0 into V0 (doesn't touch Q region)
  {
    uint4 va  = *(const uint4*)&vgc[(size_t)(b*CH + r0)*NN + mbase + c0];
    uint4 vb4 = *(const uint4*)&vgc[(size_t)(b*CH + r1)*NN + mbase + c1];
    *(uint4*)(smem + 16384 + swz(r0, c0*2)) = va;
    *(uint4*)(smem + 16384 + swz(r1, c1*2)) = vb4;
  }
  // K A-frags for kt=0: direct global load (16B contiguous in kgT)
  const bf16* kb = kgT + (size_t)(b*NN + mbase + wv*16 + ln)*64;
  short8 ak0 = *(const short8*)&kb[quad*8];
  short8 ak1 = *(const short8*)&kb[32 + quad*8];
  __syncthreads();   // V0 visible; Q hoists done before P0 writes

  f4 accO0 = (f4){0.f,0.f,0.f,0.f};   // (i=0 c-tile, j=0 n-strip)
  f4 accO1 = (f4){0.f,0.f,0.f,0.f};   // (i=1, j=0)
  f4 accO2 = (f4){0.f,0.f,0.f,0.f};   // (i=0, j=1)
  f4 accO3 = (f4){0.f,0.f,0.f,0.f};   // (i=1, j=1)
  float lacc0 = 0.f, lacc1 = 0.f, lacc2 = 0.f, lacc3 = 0.f;

  uint4 vr0, vr1;
  short8 an0, an1;
  for (int kt = 0; kt < KTPS; ++kt) {
    const int po = (kt & 1) * 8192;
    const int vo = 16384 + (kt & 1) * 8192;
    // ---- prefetch next tile unconditionally (index clamped) ----
    {
      int ktn = (kt + 1 < KTPS) ? kt + 1 : kt;
      int m1 = mbase + ktn*64;
      vr0 = *(const uint4*)&vgc[(size_t)(b*CH + r0)*NN + m1 + c0];
      vr1 = *(const uint4*)&vgc[(size_t)(b*CH + r1)*NN + m1 + c1];
      an0 = *(const short8*)&kb[(size_t)ktn*4096 + quad*8];
      an1 = *(const short8*)&kb[(size_t)ktn*4096 + 32 + quad*8];
    }

    // ---- S^T = K Q^T: wave's m-strip only (A = K direct-loaded frags) ----
    f4 accS0, accS1, accS2, accS3;
    __builtin_amdgcn_s_setprio(1);
    {
      f4 z = (f4){0.f,0.f,0.f,0.f};
      z = MFMA16(ak0, bq00, z, 0, 0, 0);
      accS0 = MFMA16(ak1, bq01, z, 0, 0, 0);
    }
    {
      f4 z = (f4){0.f,0.f,0.f,0.f};
      z = MFMA16(ak0, bq10, z, 0, 0, 0);
      accS1 = MFMA16(ak1, bq11, z, 0, 0, 0);
    }
    {
      f4 z = (f4){0.f,0.f,0.f,0.f};
      z = MFMA16(ak0, bq20, z, 0, 0, 0);
      accS2 = MFMA16(ak1, bq21, z, 0, 0, 0);
    }
    {
      f4 z = (f4){0.f,0.f,0.f,0.f};
      z = MFMA16(ak0, bq30, z, 0, 0, 0);
      accS3 = MFMA16(ak1, bq31, z, 0, 0, 0);
    }
    __builtin_amdgcn_s_setprio(0);
    // ---- P = exp2(S): lane holds m=wv*16+quad*4+r, n=nt*16+ln ----
    {
      float p0 = fexp2(accS0[0]), p1 = fexp2(accS0[1]);
      float p2 = fexp2(accS0[2]), p3 = fexp2(accS0[3]);
      lacc0 += (p0 + p1) + (p2 + p3);
      uint2 pk; pk.x = pkbf(p0, p1); pk.y = pkbf(p2, p3);
      *(uint2*)(smem + po + swz(0*16 + ln, wv*32 + quad*8)) = pk;
    }
    {
      float p0 = fexp2(accS1[0]), p1 = fexp2(accS1[1]);
      float p2 = fexp2(accS1[2]), p3 = fexp2(accS1[3]);
      lacc1 += (p0 + p1) + (p2 + p3);
      uint2 pk; pk.x = pkbf(p0, p1); pk.y = pkbf(p2, p3);
      *(uint2*)(smem + po + swz(1*16 + ln, wv*32 + quad*8)) = pk;
    }
    {
      float p0 = fexp2(accS2[0]), p1 = fexp2(accS2[1]);
      float p2 = fexp2(accS2[2]), p3 = fexp2(accS2[3]);
      lacc2 += (p0 + p1) + (p2 + p3);
      uint2 pk; pk.x = pkbf(p0, p1); pk.y = pkbf(p2, p3);
      *(uint2*)(smem + po + swz(2*16 + ln, wv*32 + quad*8)) = pk;
    }
    {
      float p0 = fexp2(accS3[0]), p1 = fexp2(accS3[1]);
      float p2 = fexp2(accS3[2]), p3 = fexp2(accS3[3]);
      lacc3 += (p0 + p1) + (p2 + p3);
      uint2 pk; pk.x = pkbf(p0, p1); pk.y = pkbf(p2, p3);
      *(uint2*)(smem + po + swz(3*16 + ln, wv*32 + quad*8)) = pk;
    }
    // ---- LDS-only barrier: P[kt&1]/V[kt&1] visible, vmcnt NOT drained ----
    sync_lds_only();

    // ---- O += P V'^T, 2x2 tiling: A(j)=P rows nw*32+j*16, B(i)=V rows
    //      cw*32+i*16 -> 8 LDS reads, 8 MFMA ----
    short8 ap00 = *(const short8*)(smem + po + swz(nw*32 + 0*16 + ln, quad*16));
    short8 ap01 = *(const short8*)(smem + po + swz(nw*32 + 0*16 + ln, 64 + quad*16));
    short8 ap10 = *(const short8*)(smem + po + swz(nw*32 + 1*16 + ln, quad*16));
    short8 ap11 = *(const short8*)(smem + po + swz(nw*32 + 1*16 + ln, 64 + quad*16));
    short8 bv00 = *(const short8*)(smem + vo + swz(cw*32 + 0*16 + ln, quad*16));
    short8 bv01 = *(const short8*)(smem + vo + swz(cw*32 + 0*16 + ln, 64 + quad*16));
    short8 bv10 = *(const short8*)(smem + vo + swz(cw*32 + 1*16 + ln, quad*16));
    short8 bv11 = *(const short8*)(smem + vo + swz(cw*32 + 1*16 + ln, 64 + quad*16));
    __builtin_amdgcn_s_setprio(1);
    accO0 = MFMA16(ap00, bv00, accO0, 0, 0, 0);
    accO0 = MFMA16(ap01, bv01, accO0, 0, 0, 0);
    accO1 = MFMA16(ap00, bv10, accO1, 0, 0, 0);
    accO1 = MFMA16(ap01, bv11, accO1, 0, 0, 0);
    accO2 = MFMA16(ap10, bv00, accO2, 0, 0, 0);
    accO2 = MFMA16(ap11, bv01, accO2, 0, 0, 0);
    accO3 = MFMA16(ap10, bv10, accO3, 0, 0, 0);
    accO3 = MFMA16(ap11, bv11, accO3, 0, 0, 0);
    __builtin_amdgcn_s_setprio(0);
    // ---- write next V into the other buffer; rotate K frags ----
    if (kt + 1 < KTPS) {
      int vn = 16384 + ((kt+1) & 1) * 8192;
      *(uint4*)(smem + vn + swz(r0, c0*2)) = vr0;
      *(uint4*)(smem + vn + swz(r1, c1*2)) = vr1;
    }
    ak0 = an0; ak1 = an1;
  }

  // ---- store partials bf16 [c][n]: accO(i,j) -> c = cw*32+i*16+ln,
  //      n = nw*32+j*16+quad*4 (uint2 = 4 consecutive n) ----
  size_t pbase = ((size_t)(b*NT + tile)*KS + split)*4096;
  ushort* pp = part + pbase;
  {
    uint2 pk; pk.x = pkbf(accO0[0], accO0[1]); pk.y = pkbf(accO0[2], accO0[3]);
    *(uint2*)&pp[(cw*32 + 0*16 + ln)*64 + nw*32 + 0*16 + quad*4] = pk;
  }
  {
    uint2 pk; pk.x = pkbf(accO1[0], accO1[1]); pk.y = pkbf(accO1[2], accO1[3]);
    *(uint2*)&pp[(cw*32 + 1*16 + ln)*64 + nw*32 + 0*16 + quad*4] = pk;
  }
  {
    uint2 pk; pk.x = pkbf(accO2[0], accO2[1]); pk.y = pkbf(accO2[2], accO2[3]);
    *(uint2*)&pp[(cw*32 + 0*16 + ln)*64 + nw*32 + 1*16 + quad*4] = pk;
  }
  {
    uint2 pk; pk.x = pkbf(accO3[0], accO3[1]); pk.y = pkbf(accO3[2], accO3[3]);
    *(uint2*)&pp[(cw*32 + 1*16 + ln)*64 + nw*32 + 1*16 + quad*4] = pk;
  }
  // ---- l: butterfly quads within wave, then cross-wave via LDS ----
  {
    float s = lacc0;
    s += __shfl_xor(s, 16); s += __shfl_xor(s, 32);
    if (quad == 0) lred[wv*64 + 0*16 + ln] = s;
  }
  {
    float s = lacc1;
    s += __shfl_xor(s, 16); s += __shfl_xor(s, 32);
    if (quad == 0) lred[wv*64 + 1*16 + ln] = s;
  }
  {
    float s = lacc2;
    s += __shfl_xor(s, 16); s += __shfl_xor(s, 32);
    if (quad == 0) lred[wv*64 + 2*16 + ln] = s;
  }
  {
    float s = lacc3;
    s += __shfl_xor(s, 16); s += __shfl_xor(s, 32);
    if (quad == 0) lred[wv*64 + 3*16 + ln] = s;
  }
  __syncthreads();
  if (tid < 64) {
    size_t mlb = ((size_t)(b*NT + tile)*KS + split)*64;
    pml[mlb + tid] = (lred[tid] + lred[64 + tid]) + (lred[128 + tid] + lred[192 + tid]);
  }
}

// ---------------------------------------------------------------------------
// attn_reduce: PURE STREAMING (out-conv already folded into V'):
// out[c][n] = sum_s part[s][c][n] / l[n] + outb[c] + x[c][n].
// One block per (b, tile); coalesced uint2 part reads, float4 x/out.
// ---------------------------------------------------------------------------
__global__ __launch_bounds__(256) void attn_reduce(
    const ushort* __restrict__ part, const float* __restrict__ pml,
    const float* __restrict__ x, const float* __restrict__ outb,
    float* __restrict__ out)
{
  __shared__ float linv[64];
  __shared__ float ob[64];

  int tid = threadIdx.x;
  int blk = blockIdx.x;
  int b = blk / NT, tile = blk % NT;
  size_t base = (size_t)(b*NT + tile)*KS;

  if (tid < 64) {
    float l = 0.f;
    #pragma unroll
    for (int s=0;s<KS;++s) l += pml[(base+s)*64 + tid];
    linv[tid] = 1.0f / l;
    ob[tid] = outb[tid];
  }
  __syncthreads();

  // 1024 uint2-chunks (4 n's at fixed c). Wave: q=tid&15 spans a full 128B
  // row, c=tid>>4 -> 4 contiguous rows -> 512B contiguous per instruction.
  #pragma unroll
  for (int j = 0; j < 4; ++j) {
    int idx = j*256 + tid;
    int c = idx >> 4, q = idx & 15;
    float a0=0.f, a1=0.f, a2=0.f, a3=0.f;
    #pragma unroll
    for (int s = 0; s < KS; ++s) {
      uint2 v = *(const uint2*)&part[(base+s)*4096 + (size_t)c*64 + q*4];
      a0 += bu2f((ushort)(v.x & 0xffff)); a1 += bu2f((ushort)(v.x >> 16));
      a2 += bu2f((ushort)(v.y & 0xffff)); a3 += bu2f((ushort)(v.y >> 16));
    }
    int nl = q*4;
    size_t gidx = (size_t)(b*CH + c)*NN + tile*64 + nl;
    float4 xv = *(const float4*)&x[gidx];
    float bc = ob[c];
    float4 o;
    o.x = a0*linv[nl+0] + bc + xv.x;
    o.y = a1*linv[nl+1] + bc + xv.y;
    o.z = a2*linv[nl+2] + bc + xv.z;
    o.w = a3*linv[nl+3] + bc + xv.w;
    *(float4*)&out[gidx] = o;
  }
}

extern "C" void kernel_launch(void* const* d_in, const int* in_sizes, int n_in,
                              void* d_out, int out_size, void* d_ws, size_t ws_size,
                              hipStream_t stream) {
  const float* x    = (const float*)d_in[0];
  const float* q1w  = (const float*)d_in[1];
  const float* q1g  = (const float*)d_in[2];
  const float* q1b  = (const float*)d_in[3];
  const float* q2w  = (const float*)d_in[4];
  const float* q2g  = (const float*)d_in[5];
  const float* q2b  = (const float*)d_in[6];
  const float* q3w  = (const float*)d_in[7];
  const float* q3g  = (const float*)d_in[8];
  const float* q3b  = (const float*)d_in[9];
  const float* khw  = (const float*)d_in[10];
  const float* khb  = (const float*)d_in[11];
  const float* klw  = (const float*)d_in[12];
  const float* klb  = (const float*)d_in[13];
  const float* kfw  = (const float*)d_in[14];
  const float* kfb  = (const float*)d_in[15];
  const float* vbg  = (const float*)d_in[16];
  const float* vbb  = (const float*)d_in[17];
  const float* vw   = (const float*)d_in[18];
  const float* vb   = (const float*)d_in[19];
  const float* outw = (const float*)d_in[20];
  const float* outb = (const float*)d_in[21];

  char*   wsb  = (char*)d_ws;
  float*  biasf= (float*)(wsb + OFF_BIAS);
  bf16*   wh   = (bf16*)(wsb + OFF_WH_B);
  bf16*   lowg = (bf16*)(wsb + OFF_LOW_B);
  bf16*   qgT  = (bf16*)(wsb + OFF_Q_B);
  bf16*   kgT  = (bf16*)(wsb + OFF_K_B);
  bf16*   vgc  = (bf16*)(wsb + OFF_V_B);
  ushort* part = (ushort*)(wsb + OFF_P_B);
  float*  pml  = (float*)(wsb + OFF_ML_B);

  hipLaunchKernelGGL(setup_fold, dim3(16), dim3(256), 0, stream,
                     q1w,q1g,q1b,q2w,q2g,q2b,q3w,q3g,q3b,
                     khw,khb,klw,klb,kfw,kfb,vbg,vbb,vw,vb,outw, biasf, wh);
  hipLaunchKernelGGL(pool_low, dim3(BATCH*CH*NN/1024), dim3(256), 0, stream, x, lowg);
  hipLaunchKernelGGL(qkv_kernel, dim3(BATCH*NT), dim3(256), 0, stream,
                     x, biasf, wh, lowg, qgT, kgT, vgc);
  hipLaunchKernelGGL(attn_partial, dim3(BATCH*NT*KS), dim3(256), 0, stream,
                     qgT, kgT, vgc, part, pml);
  hipLaunchKernelGGL(attn_reduce, dim3(BATCH*NT), dim3(256), 0, stream,
                     part, pml, x, outb, (float*)d_out);
}

// Round 10
// 142.253 us; speedup vs baseline: 1.0453x; 1.0453x over previous
//
#include <hip/hip_runtime.h>
#include <hip/hip_bf16.h>

// IRChannelAttention on MI355X. Round 26: merge setup_fold + pool_low.
// r23-r25 post-mortem: three neutral rounds on attn_partial micro-structure
// (vmcnt drain, 2x2 PV tiling, setprio) -> attn is at a latency/occupancy
// equilibrium; keep the best-measured r22 form exactly. The harness's 2x43.5us
// 256MB ws-poison fills (~87us, 77% HBM) dominate the window and are fixed.
// Controllable lever this round: the dispatch chain. setup_fold (16 blk) ran
// serially before the independent pool_low (800 blk). Merged into ONE kernel
// (blk<16 = setup via direct global reads -- tables are L1/L2-resident, so
// no 64KB LDS staging that would throttle pool occupancy; blk>=16 = pool).
// Saves one launch + overlaps setup behind pool.
// B=2, C=64, H=W=80, N=6400. fp32 global I/O, bf16 ws intermediates.

#define BATCH 2
#define CH 64
#define HH 80
#define WW 80
#define NN 6400
#define NT 100          // NN / 64
#define KS 5            // key splits (divides NT)
#define KTPS (NT/KS)    // 20 key tiles per split
#define EPSV 1e-5f
#define NEGBIG (-1e30f)
#define LOG2E8 0.18033688f   // log2(e)/8, folded into Q weights

typedef __hip_bfloat16 bf16;
typedef __attribute__((ext_vector_type(8))) short short8;   // MFMA A/B frag
typedef __attribute__((ext_vector_type(4))) float f4;       // MFMA C/D frag
#define MFMA16 __builtin_amdgcn_mfma_f32_16x16x32_bf16

__device__ __forceinline__ float b2f(bf16 v){ return __bfloat162float(v); }
__device__ __forceinline__ bf16 f2b(float v){ return __float2bfloat16(v); }
__device__ __forceinline__ ushort f2bu(float v){ return ((__hip_bfloat16_raw)__float2bfloat16(v)).x; }
__device__ __forceinline__ float bu2f(ushort u){
  union { unsigned int i; float f; } w; w.i = ((unsigned int)u) << 16; return w.f;
}
__device__ __forceinline__ unsigned pkbf(float a, float b){   // packed bf16x2
  union { __hip_bfloat162 h2; unsigned u; } cv;
  cv.h2 = __float22bfloat162_rn(make_float2(a, b));
  return cv.u;
}
__device__ __forceinline__ float fexp2(float x){
#if __has_builtin(__builtin_amdgcn_exp2f)
  return __builtin_amdgcn_exp2f(x);
#else
  return exp2f(x);
#endif
}
// byte offset into a [64][64] bf16 tile (128B rows), st-16x32 XOR swizzle.
__device__ __forceinline__ int swz(int row, int colb){
  return row*128 + (colb ^ ((row & 7) << 4));
}

// ws layout (bytes)
#define OFF_BIAS 0                              // 192 fp32: BQ(scaled) BK BVP
#define OFF_WH_B 768                            // 4 x 4096 bf16: wq | wvp | wa1 | wa2m  ([co][ci])
#define OFF_LOW_B (768 + 32768)                 // lowg bf16 [b][c][n]
#define OFF_Q_B   (OFF_LOW_B + BATCH*CH*NN*2)   // qgT bf16 [b][n][c]
#define OFF_K_B   (OFF_Q_B   + BATCH*CH*NN*2)   // kgT bf16 [b][n][c]
#define OFF_V_B   (OFF_K_B   + BATCH*CH*NN*2)   // vgc (=V') bf16 [b][c][n]
#define OFF_P_B   (OFF_V_B   + BATCH*CH*NN*2)   // part bf16 [(b*NT+t)*KS+s][c][n]
#define OFF_ML_B  (OFF_P_B   + BATCH*NT*KS*4096*2) // l fp32 [(b*NT+t)*KS+s][64]
// total ~15.3 MB

// ---------------------------------------------------------------------------
// setup_pool: blocks 0..15 = weight folding (direct global reads; tables
// kfw/khw/klw/outw/vw are <=16KB each, L1/L2-resident across 16 blocks).
// Blocks 16..815 = pool_low (4 outputs/thread, float4 sliding windows).
// Only 256B LDS (sbv) -> pool occupancy unthrottled.
// Folds: wq (+BN+softmax scale), wa1/wa2m (K chain), wvp = Wo @ (vw*bnscale);
// weights stored [co][ci].
// ---------------------------------------------------------------------------
__global__ __launch_bounds__(256) void setup_pool(
    const float* __restrict__ q1w, const float* __restrict__ q1g, const float* __restrict__ q1b,
    const float* __restrict__ q2w, const float* __restrict__ q2g, const float* __restrict__ q2b,
    const float* __restrict__ q3w, const float* __restrict__ q3g, const float* __restrict__ q3b,
    const float* __restrict__ khw, const float* __restrict__ khb,
    const float* __restrict__ klw, const float* __restrict__ klb,
    const float* __restrict__ kfw, const float* __restrict__ kfb,
    const float* __restrict__ vg,  const float* __restrict__ vbnb,
    const float* __restrict__ vw,  const float* __restrict__ vb,
    const float* __restrict__ outw,
    const float* __restrict__ x,
    float* __restrict__ biasf, bf16* __restrict__ wh, bf16* __restrict__ lowg)
{
  __shared__ float sbv[64];    // bv_old[j] = vb[j] + vw[j]@vbnb  (blk 0 only)

  int tid = threadIdx.x;
  int blk = blockIdx.x;

  if (blk < 16) {
    // ================= setup branch =================
    float rs = rsqrtf(1.0f + EPSV);

    bf16* wq   = wh;
    bf16* wvp  = wh + 4096;
    bf16* wa1  = wh + 8192;
    bf16* wa2m = wh + 12288;

    int t = blk*256 + tid;
    int ci = t & 63, co = t >> 6;        // ci = lane-fast
    int o = co*64 + ci;                  // [co][ci] storage (ci contiguous)

    float w = 0.f, g;
    if (co < 21)      { g = q1g[co];    w = (ci < 21)              ? q1w[co*21 + ci]            : 0.f; }
    else if (co < 42) { g = q2g[co-21]; w = (ci >= 21 && ci < 42)  ? q2w[(co-21)*21 + (ci-21)]  : 0.f; }
    else              { g = q3g[co-42]; w = (ci >= 42)             ? q3w[(co-42)*22 + (ci-42)]  : 0.f; }
    wq[o] = f2b(w * g * rs * LOG2E8);

    float a1 = 0.f, a2 = 0.f;
    #pragma unroll
    for (int j = 0; j < 32; ++j) {
      a1 += kfw[co*64 + j]      * khw[j*64 + ci];
      a2 += kfw[co*64 + 32 + j] * klw[j*64 + ci];
    }
    wa1[o]  = f2b(a1);
    wa2m[o] = f2b(a2 - a1);              // K = A1@x + (A2-A1)@low + bK

    // V' weight: wvp[co][ci] = rs*vg[ci] * sum_j outw[co][j]*vw[j][ci]
    float av = 0.f;
    #pragma unroll
    for (int j = 0; j < 64; ++j)
      av += outw[co*64 + j] * vw[j*64 + ci];
    wvp[o] = f2b(av * vg[ci] * rs);

    if (blk == 0 && tid < 64) {
      int c2 = tid;
      // sbv[j] computed by lane j of this single wave; wave-local LDS
      // ordering (same-wave write -> later read) suffices.
      float bvo = vb[c2];
      for (int i2 = 0; i2 < 64; ++i2) bvo += vw[c2*64 + i2] * vbnb[i2];
      sbv[c2] = bvo;

      float bq;
      if (c2 < 21)      bq = q1b[c2];
      else if (c2 < 42) bq = q2b[c2-21];
      else              bq = q3b[c2-42];
      biasf[c2] = bq * LOG2E8;
      float bk = kfb[c2];
      #pragma unroll
      for (int j = 0; j < 32; ++j) {
        bk += kfw[c2*64 + j]      * khb[j];
        bk += kfw[c2*64 + 32 + j] * klb[j];
      }
      biasf[64 + c2] = bk;
      // folded V' bias: bvp = Wo @ bv_old
      float bvp = 0.f;
      #pragma unroll
      for (int j = 0; j < 64; ++j) bvp += outw[c2*64 + j] * sbv[j];
      biasf[128 + c2] = bvp;
    }
    return;
  }

  // ================= pool branch =================
  int t4 = ((blk - 16)*256 + tid)*4;
  int bc = t4 / NN; int n = t4 % NN;
  int h = n / WW, w0 = n % WW;                 // w0 multiple of 4
  const float* p = x + bc*NN;
  float m5[4], m3[4];
  #pragma unroll
  for (int j=0;j<4;++j){ m5[j]=NEGBIG; m3[j]=NEGBIG; }
  #pragma unroll
  for (int dh = -2; dh <= 2; ++dh) {
    int hh = h + dh; if (hh < 0 || hh >= HH) continue;
    float r[12];
    const float* row = p + hh*WW;
    if (w0 >= 4)      { float4 a = *(const float4*)&row[w0-4]; r[0]=a.x;r[1]=a.y;r[2]=a.z;r[3]=a.w; }
    else              { r[0]=NEGBIG;r[1]=NEGBIG;r[2]=NEGBIG;r[3]=NEGBIG; }
    { float4 a = *(const float4*)&row[w0]; r[4]=a.x;r[5]=a.y;r[6]=a.z;r[7]=a.w; }
    if (w0 + 7 < WW)  { float4 a = *(const float4*)&row[w0+4]; r[8]=a.x;r[9]=a.y;r[10]=a.z;r[11]=a.w; }
    else              { r[8]=NEGBIG;r[9]=NEGBIG;r[10]=NEGBIG;r[11]=NEGBIG; }
    bool in3 = (dh >= -1 && dh <= 1);
    #pragma unroll
    for (int j=0;j<4;++j) {
      float v3 = fmaxf(fmaxf(r[3+j], r[4+j]), r[5+j]);
      float v5 = fmaxf(fmaxf(r[2+j], v3), r[6+j]);
      m5[j] = fmaxf(m5[j], v5);
      if (in3) m3[j] = fmaxf(m3[j], v3);
    }
  }
  ushort4 o;
  o.x = f2bu(0.5f*(m3[0]+m5[0]));
  o.y = f2bu(0.5f*(m3[1]+m5[1]));
  o.z = f2bu(0.5f*(m3[2]+m5[2]));
  o.w = f2bu(0.5f*(m3[3]+m5[3]));
  *(ushort4*)&lowg[t4] = o;
}

// ---------------------------------------------------------------------------
// qkv_kernel (MFMA): one 64-n tile per block, grid B*NT = 200, 4 waves.
// Stage x(f32->bf16) and low transposed into LDS [n][ci] (swizzled).
// Weights direct-from-global ([co][ci], 16B frags). 32 MFMA/wave.
// ---------------------------------------------------------------------------
__global__ __launch_bounds__(256, 2) void qkv_kernel(
    const float* __restrict__ x, const float* __restrict__ biasf,
    const bf16* __restrict__ wh, const bf16* __restrict__ lowg,
    bf16* __restrict__ qgT, bf16* __restrict__ kgT, bf16* __restrict__ vgc)
{
  __shared__ __align__(16) char xT[8192];   // [64n][64ci] bf16, swizzled
  __shared__ __align__(16) char lT[8192];
  __shared__ float bias[192];

  int tid = threadIdx.x;
  int blk = blockIdx.x;
  int b = blk / NT, tile = blk % NT;
  int n0 = tile*64;
  int wv = tid >> 6, lane = tid & 63, ln = lane & 15, quad = lane >> 4;

  if (tid < 192) bias[tid] = biasf[tid];

  // ---- transpose-stage: thread owns 4c x 4n (c=cq*4, n=nq*4) ----
  {
    int cq = tid & 15, nq = tid >> 4;
    const float* xp = x + (size_t)(b*CH + cq*4)*NN + n0 + nq*4;
    float4 x0 = *(const float4*)&xp[0*NN];
    float4 x1 = *(const float4*)&xp[(size_t)1*NN];
    float4 x2 = *(const float4*)&xp[(size_t)2*NN];
    float4 x3 = *(const float4*)&xp[(size_t)3*NN];
    const bf16* lp = lowg + (size_t)(b*CH + cq*4)*NN + n0 + nq*4;
    uint2 l0 = *(const uint2*)&lp[0*NN];
    uint2 l1 = *(const uint2*)&lp[(size_t)1*NN];
    uint2 l2 = *(const uint2*)&lp[(size_t)2*NN];
    uint2 l3 = *(const uint2*)&lp[(size_t)3*NN];
    uint2 w;
    // j = 0
    w.x = pkbf(x0.x, x1.x); w.y = pkbf(x2.x, x3.x);
    *(uint2*)(xT + swz(nq*4+0, cq*8)) = w;
    w.x = (l0.x & 0xffffu) | ((l1.x & 0xffffu) << 16);
    w.y = (l2.x & 0xffffu) | ((l3.x & 0xffffu) << 16);
    *(uint2*)(lT + swz(nq*4+0, cq*8)) = w;
    // j = 1
    w.x = pkbf(x0.y, x1.y); w.y = pkbf(x2.y, x3.y);
    *(uint2*)(xT + swz(nq*4+1, cq*8)) = w;
    w.x = (l0.x >> 16) | ((l1.x >> 16) << 16);
    w.y = (l2.x >> 16) | ((l3.x >> 16) << 16);
    *(uint2*)(lT + swz(nq*4+1, cq*8)) = w;
    // j = 2
    w.x = pkbf(x0.z, x1.z); w.y = pkbf(x2.z, x3.z);
    *(uint2*)(xT + swz(nq*4+2, cq*8)) = w;
    w.x = (l0.y & 0xffffu) | ((l1.y & 0xffffu) << 16);
    w.y = (l2.y & 0xffffu) | ((l3.y & 0xffffu) << 16);
    *(uint2*)(lT + swz(nq*4+2, cq*8)) = w;
    // j = 3
    w.x = pkbf(x0.w, x1.w); w.y = pkbf(x2.w, x3.w);
    *(uint2*)(xT + swz(nq*4+3, cq*8)) = w;
    w.x = (l0.y >> 16) | ((l1.y >> 16) << 16);
    w.y = (l2.y >> 16) | ((l3.y >> 16) << 16);
    *(uint2*)(lT + swz(nq*4+3, cq*8)) = w;
  }
  __syncthreads();

  // ---- xT B-frags (cols n = nt*16+ln), named ----
  short8 xb00 = *(const short8*)(xT + swz(0*16 + ln, quad*16));
  short8 xb01 = *(const short8*)(xT + swz(0*16 + ln, 64 + quad*16));
  short8 xb10 = *(const short8*)(xT + swz(1*16 + ln, quad*16));
  short8 xb11 = *(const short8*)(xT + swz(1*16 + ln, 64 + quad*16));
  short8 xb20 = *(const short8*)(xT + swz(2*16 + ln, quad*16));
  short8 xb21 = *(const short8*)(xT + swz(2*16 + ln, 64 + quad*16));
  short8 xb30 = *(const short8*)(xT + swz(3*16 + ln, quad*16));
  short8 xb31 = *(const short8*)(xT + swz(3*16 + ln, 64 + quad*16));
  // V' A-frags: rows n = wv*16+ln (dup load, avoids runtime-indexed select)
  short8 xa0 = *(const short8*)(xT + swz(wv*16 + ln, quad*16));
  short8 xa1 = *(const short8*)(xT + swz(wv*16 + ln, 64 + quad*16));

  int cb = wv*16 + quad*4;             // first of 4 output rows (Q/K) / n (V')
  const bf16* wqp  = wh;               // [co][ci]
  const bf16* wvpp = wh + 4096;
  const bf16* wa1p = wh + 8192;
  const bf16* wa2p = wh + 12288;
  int wrow = (wv*16 + ln)*64;

  // ================= V' : D[n][co] =================
  {
    {
      short8 w0 = *(const short8*)&wvpp[(0*16 + ln)*64 + quad*8];
      short8 w1 = *(const short8*)&wvpp[(0*16 + ln)*64 + 32 + quad*8];
      float bv = bias[128 + 0*16 + ln];
      f4 a = (f4){bv, bv, bv, bv};
      a = MFMA16(xa0, w0, a, 0, 0, 0);
      a = MFMA16(xa1, w1, a, 0, 0, 0);
      uint2 pk; pk.x = pkbf(a[0], a[1]); pk.y = pkbf(a[2], a[3]);
      *(uint2*)&vgc[(size_t)(b*CH + 0*16 + ln)*NN + n0 + cb] = pk;
    }
    {
      short8 w0 = *(const short8*)&wvpp[(1*16 + ln)*64 + quad*8];
      short8 w1 = *(const short8*)&wvpp[(1*16 + ln)*64 + 32 + quad*8];
      float bv = bias[128 + 1*16 + ln];
      f4 a = (f4){bv, bv, bv, bv};
      a = MFMA16(xa0, w0, a, 0, 0, 0);
      a = MFMA16(xa1, w1, a, 0, 0, 0);
      uint2 pk; pk.x = pkbf(a[0], a[1]); pk.y = pkbf(a[2], a[3]);
      *(uint2*)&vgc[(size_t)(b*CH + 1*16 + ln)*NN + n0 + cb] = pk;
    }
    {
      short8 w0 = *(const short8*)&wvpp[(2*16 + ln)*64 + quad*8];
      short8 w1 = *(const short8*)&wvpp[(2*16 + ln)*64 + 32 + quad*8];
      float bv = bias[128 + 2*16 + ln];
      f4 a = (f4){bv, bv, bv, bv};
      a = MFMA16(xa0, w0, a, 0, 0, 0);
      a = MFMA16(xa1, w1, a, 0, 0, 0);
      uint2 pk; pk.x = pkbf(a[0], a[1]); pk.y = pkbf(a[2], a[3]);
      *(uint2*)&vgc[(size_t)(b*CH + 2*16 + ln)*NN + n0 + cb] = pk;
    }
    {
      short8 w0 = *(const short8*)&wvpp[(3*16 + ln)*64 + quad*8];
      short8 w1 = *(const short8*)&wvpp[(3*16 + ln)*64 + 32 + quad*8];
      float bv = bias[128 + 3*16 + ln];
      f4 a = (f4){bv, bv, bv, bv};
      a = MFMA16(xa0, w0, a, 0, 0, 0);
      a = MFMA16(xa1, w1, a, 0, 0, 0);
      uint2 pk; pk.x = pkbf(a[0], a[1]); pk.y = pkbf(a[2], a[3]);
      *(uint2*)&vgc[(size_t)(b*CH + 3*16 + ln)*NN + n0 + cb] = pk;
    }
  }

  // ================= Q : D[co][n], ReLU =================
  {
    short8 wq0 = *(const short8*)&wqp[wrow + quad*8];
    short8 wq1 = *(const short8*)&wqp[wrow + 32 + quad*8];
    f4 bQ;
    bQ[0] = bias[cb+0]; bQ[1] = bias[cb+1]; bQ[2] = bias[cb+2]; bQ[3] = bias[cb+3];
    {
      f4 a = bQ;
      a = MFMA16(wq0, xb00, a, 0, 0, 0);
      a = MFMA16(wq1, xb01, a, 0, 0, 0);
      uint2 pk;
      pk.x = pkbf(fmaxf(a[0],0.f), fmaxf(a[1],0.f));
      pk.y = pkbf(fmaxf(a[2],0.f), fmaxf(a[3],0.f));
      *(uint2*)&qgT[(size_t)(b*NN + n0 + 0*16 + ln)*64 + cb] = pk;
    }
    {
      f4 a = bQ;
      a = MFMA16(wq0, xb10, a, 0, 0, 0);
      a = MFMA16(wq1, xb11, a, 0, 0, 0);
      uint2 pk;
      pk.x = pkbf(fmaxf(a[0],0.f), fmaxf(a[1],0.f));
      pk.y = pkbf(fmaxf(a[2],0.f), fmaxf(a[3],0.f));
      *(uint2*)&qgT[(size_t)(b*NN + n0 + 1*16 + ln)*64 + cb] = pk;
    }
    {
      f4 a = bQ;
      a = MFMA16(wq0, xb20, a, 0, 0, 0);
      a = MFMA16(wq1, xb21, a, 0, 0, 0);
      uint2 pk;
      pk.x = pkbf(fmaxf(a[0],0.f), fmaxf(a[1],0.f));
      pk.y = pkbf(fmaxf(a[2],0.f), fmaxf(a[3],0.f));
      *(uint2*)&qgT[(size_t)(b*NN + n0 + 2*16 + ln)*64 + cb] = pk;
    }
    {
      f4 a = bQ;
      a = MFMA16(wq0, xb30, a, 0, 0, 0);
      a = MFMA16(wq1, xb31, a, 0, 0, 0);
      uint2 pk;
      pk.x = pkbf(fmaxf(a[0],0.f), fmaxf(a[1],0.f));
      pk.y = pkbf(fmaxf(a[2],0.f), fmaxf(a[3],0.f));
      *(uint2*)&qgT[(size_t)(b*NN + n0 + 3*16 + ln)*64 + cb] = pk;
    }
  }

  // ================= K : D[co][n] = A1@x + (A2-A1)@low + bK =================
  {
    short8 wa10 = *(const short8*)&wa1p[wrow + quad*8];
    short8 wa11 = *(const short8*)&wa1p[wrow + 32 + quad*8];
    short8 wm0  = *(const short8*)&wa2p[wrow + quad*8];
    short8 wm1  = *(const short8*)&wa2p[wrow + 32 + quad*8];
    short8 lb00 = *(const short8*)(lT + swz(0*16 + ln, quad*16));
    short8 lb01 = *(const short8*)(lT + swz(0*16 + ln, 64 + quad*16));
    short8 lb10 = *(const short8*)(lT + swz(1*16 + ln, quad*16));
    short8 lb11 = *(const short8*)(lT + swz(1*16 + ln, 64 + quad*16));
    short8 lb20 = *(const short8*)(lT + swz(2*16 + ln, quad*16));
    short8 lb21 = *(const short8*)(lT + swz(2*16 + ln, 64 + quad*16));
    short8 lb30 = *(const short8*)(lT + swz(3*16 + ln, quad*16));
    short8 lb31 = *(const short8*)(lT + swz(3*16 + ln, 64 + quad*16));
    f4 bK;
    bK[0] = bias[64+cb+0]; bK[1] = bias[64+cb+1];
    bK[2] = bias[64+cb+2]; bK[3] = bias[64+cb+3];
    {
      f4 a = bK;
      a = MFMA16(wa10, xb00, a, 0, 0, 0);
      a = MFMA16(wa11, xb01, a, 0, 0, 0);
      a = MFMA16(wm0,  lb00, a, 0, 0, 0);
      a = MFMA16(wm1,  lb01, a, 0, 0, 0);
      uint2 pk; pk.x = pkbf(a[0], a[1]); pk.y = pkbf(a[2], a[3]);
      *(uint2*)&kgT[(size_t)(b*NN + n0 + 0*16 + ln)*64 + cb] = pk;
    }
    {
      f4 a = bK;
      a = MFMA16(wa10, xb10, a, 0, 0, 0);
      a = MFMA16(wa11, xb11, a, 0, 0, 0);
      a = MFMA16(wm0,  lb10, a, 0, 0, 0);
      a = MFMA16(wm1,  lb11, a, 0, 0, 0);
      uint2 pk; pk.x = pkbf(a[0], a[1]); pk.y = pkbf(a[2], a[3]);
      *(uint2*)&kgT[(size_t)(b*NN + n0 + 1*16 + ln)*64 + cb] = pk;
    }
    {
      f4 a = bK;
      a = MFMA16(wa10, xb20, a, 0, 0, 0);
      a = MFMA16(wa11, xb21, a, 0, 0, 0);
      a = MFMA16(wm0,  lb20, a, 0, 0, 0);
      a = MFMA16(wm1,  lb21, a, 0, 0, 0);
      uint2 pk; pk.x = pkbf(a[0], a[1]); pk.y = pkbf(a[2], a[3]);
      *(uint2*)&kgT[(size_t)(b*NN + n0 + 2*16 + ln)*64 + cb] = pk;
    }
    {
      f4 a = bK;
      a = MFMA16(wa10, xb30, a, 0, 0, 0);
      a = MFMA16(wa11, xb31, a, 0, 0, 0);
      a = MFMA16(wm0,  lb30, a, 0, 0, 0);
      a = MFMA16(wm1,  lb31, a, 0, 0, 0);
      uint2 pk; pk.x = pkbf(a[0], a[1]); pk.y = pkbf(a[2], a[3]);
      *(uint2*)&kgT[(size_t)(b*NN + n0 + 3*16 + ln)*64 + cb] = pk;
    }
  }
}

// ---------------------------------------------------------------------------
// attn_partial: split-K flash (r22 structure exactly -- best measured).
// S^T = K.Q^T: A = K rows (direct global from kgT [n][c]); B = Q hoisted
// (8 named short8). V cooperatively staged to LDS with one-tile-ahead
// register prefetch; P/V double buffers [64][64] bf16 pitch 64 + XOR
// swizzle -> conflict-free. ONE __syncthreads per kt. KS=5.
// ---------------------------------------------------------------------------
__global__ __launch_bounds__(256, 2) void attn_partial(
    const bf16* __restrict__ qgT, const bf16* __restrict__ kgT, const bf16* __restrict__ vgc,
    ushort* __restrict__ part, float* __restrict__ pml)
{
  // [0,8192)=P0 (aliases Q stage), [8192,16384)=P1, [16384,24576)=V0,
  // [24576,32768)=V1
  __shared__ __align__(16) char smem[32768];
  __shared__ float lred[256];

  int tid = threadIdx.x;
  int blk = blockIdx.x;
  int b = blk / (NT*KS);
  int rem = blk % (NT*KS);
  int tile = rem / KS, split = rem % KS;
  int n0 = tile*64;
  int wv = tid >> 6, lane = tid & 63, ln = lane & 15, quad = lane >> 4;
  int mbase = split*KTPS*64;

  // staging geometry (shared by Q/V stages): two 16B chunks per thread
  int r0 = tid >> 3,         c0 = (tid & 7)*8;        // chunk 0: rows 0..31
  int r1 = 32 + (tid >> 3),  c1 = (tid & 7)*8;        // chunk 1: rows 32..63

  // ---- stage Q [n][c] (swizzled), hoist ALL Q as 8 named B-frags ----
  {
    uint4 qa = *(const uint4*)&qgT[(size_t)(b*NN + n0 + r0)*64 + c0];
    uint4 qb = *(const uint4*)&qgT[(size_t)(b*NN + n0 + r1)*64 + c1];
    *(uint4*)(smem + swz(r0, c0*2)) = qa;
    *(uint4*)(smem + swz(r1, c1*2)) = qb;
  }
  __syncthreads();
  short8 bq00 = *(const short8*)(smem + swz( 0*16 + ln, quad*16));
  short8 bq01 = *(const short8*)(smem + swz( 0*16 + ln, 64 + quad*16));
  short8 bq10 = *(const short8*)(smem + swz( 1*16 + ln, quad*16));
  short8 bq11 = *(const short8*)(smem + swz( 1*16 + ln, 64 + quad*16));
  short8 bq20 = *(const short8*)(smem + swz( 2*16 + ln, quad*16));
  short8 bq21 = *(const short8*)(smem + swz( 2*16 + ln, 64 + quad*16));
  short8 bq30 = *(const short8*)(smem + swz( 3*16 + ln, quad*16));
  short8 bq31 = *(const short8*)(smem + swz( 3*16 + ln, 64 + quad*16));
  // stage V tile 0 into V0 (doesn't touch Q region)
  {
    uint4 va  = *(const uint4*)&vgc[(size_t)(b*CH + r0)*NN + mbase + c0];
    uint4 vb4 = *(const uint4*)&vgc[(size_t)(b*CH + r1)*NN + mbase + c1];
    *(uint4*)(smem + 16384 + swz(r0, c0*2)) = va;
    *(uint4*)(smem + 16384 + swz(r1, c1*2)) = vb4;
  }
  // K A-frags for kt=0: direct global load (16B contiguous in kgT)
  const bf16* kb = kgT + (size_t)(b*NN + mbase + wv*16 + ln)*64;
  short8 ak0 = *(const short8*)&kb[quad*8];
  short8 ak1 = *(const short8*)&kb[32 + quad*8];
  __syncthreads();   // V0 visible; Q hoists done before P0 writes

  f4 accO0 = (f4){0.f,0.f,0.f,0.f};
  f4 accO1 = (f4){0.f,0.f,0.f,0.f};
  f4 accO2 = (f4){0.f,0.f,0.f,0.f};
  f4 accO3 = (f4){0.f,0.f,0.f,0.f};
  float lacc0 = 0.f, lacc1 = 0.f, lacc2 = 0.f, lacc3 = 0.f;

  uint4 vr0, vr1;
  short8 an0, an1;
  for (int kt = 0; kt < KTPS; ++kt) {
    const int po = (kt & 1) * 8192;
    const int vo = 16384 + (kt & 1) * 8192;
    // ---- prefetch next tile unconditionally (index clamped) ----
    {
      int ktn = (kt + 1 < KTPS) ? kt + 1 : kt;
      int m1 = mbase + ktn*64;
      vr0 = *(const uint4*)&vgc[(size_t)(b*CH + r0)*NN + m1 + c0];
      vr1 = *(const uint4*)&vgc[(size_t)(b*CH + r1)*NN + m1 + c1];
      an0 = *(const short8*)&kb[(size_t)ktn*4096 + quad*8];
      an1 = *(const short8*)&kb[(size_t)ktn*4096 + 32 + quad*8];
    }

    // ---- S^T = K Q^T: wave's m-strip only (A = K direct-loaded frags) ----
    f4 accS0, accS1, accS2, accS3;
    {
      f4 z = (f4){0.f,0.f,0.f,0.f};
      z = MFMA16(ak0, bq00, z, 0, 0, 0);
      accS0 = MFMA16(ak1, bq01, z, 0, 0, 0);
    }
    {
      f4 z = (f4){0.f,0.f,0.f,0.f};
      z = MFMA16(ak0, bq10, z, 0, 0, 0);
      accS1 = MFMA16(ak1, bq11, z, 0, 0, 0);
    }
    {
      f4 z = (f4){0.f,0.f,0.f,0.f};
      z = MFMA16(ak0, bq20, z, 0, 0, 0);
      accS2 = MFMA16(ak1, bq21, z, 0, 0, 0);
    }
    {
      f4 z = (f4){0.f,0.f,0.f,0.f};
      z = MFMA16(ak0, bq30, z, 0, 0, 0);
      accS3 = MFMA16(ak1, bq31, z, 0, 0, 0);
    }
    // ---- P = exp2(S): lane holds m=wv*16+quad*4+r, n=nt*16+ln ----
    {
      float p0 = fexp2(accS0[0]), p1 = fexp2(accS0[1]);
      float p2 = fexp2(accS0[2]), p3 = fexp2(accS0[3]);
      lacc0 += (p0 + p1) + (p2 + p3);
      uint2 pk; pk.x = pkbf(p0, p1); pk.y = pkbf(p2, p3);
      *(uint2*)(smem + po + swz(0*16 + ln, wv*32 + quad*8)) = pk;
    }
    {
      float p0 = fexp2(accS1[0]), p1 = fexp2(accS1[1]);
      float p2 = fexp2(accS1[2]), p3 = fexp2(accS1[3]);
      lacc1 += (p0 + p1) + (p2 + p3);
      uint2 pk; pk.x = pkbf(p0, p1); pk.y = pkbf(p2, p3);
      *(uint2*)(smem + po + swz(1*16 + ln, wv*32 + quad*8)) = pk;
    }
    {
      float p0 = fexp2(accS2[0]), p1 = fexp2(accS2[1]);
      float p2 = fexp2(accS2[2]), p3 = fexp2(accS2[3]);
      lacc2 += (p0 + p1) + (p2 + p3);
      uint2 pk; pk.x = pkbf(p0, p1); pk.y = pkbf(p2, p3);
      *(uint2*)(smem + po + swz(2*16 + ln, wv*32 + quad*8)) = pk;
    }
    {
      float p0 = fexp2(accS3[0]), p1 = fexp2(accS3[1]);
      float p2 = fexp2(accS3[2]), p3 = fexp2(accS3[3]);
      lacc3 += (p0 + p1) + (p2 + p3);
      uint2 pk; pk.x = pkbf(p0, p1); pk.y = pkbf(p2, p3);
      *(uint2*)(smem + po + swz(3*16 + ln, wv*32 + quad*8)) = pk;
    }
    __syncthreads();   // P[kt&1] visible; V[kt&1] (written last iter) visible

    // ---- O += P V'^T (A = P rows of wave's n-strip, B = V') ----
    short8 ap0 = *(const short8*)(smem + po + swz(wv*16 + ln, quad*16));
    short8 ap1 = *(const short8*)(smem + po + swz(wv*16 + ln, 64 + quad*16));
    {
      short8 bv0 = *(const short8*)(smem + vo + swz(0*16 + ln, quad*16));
      short8 bv1 = *(const short8*)(smem + vo + swz(0*16 + ln, 64 + quad*16));
      accO0 = MFMA16(ap0, bv0, accO0, 0, 0, 0);
      accO0 = MFMA16(ap1, bv1, accO0, 0, 0, 0);
    }
    {
      short8 bv0 = *(const short8*)(smem + vo + swz(1*16 + ln, quad*16));
      short8 bv1 = *(const short8*)(smem + vo + swz(1*16 + ln, 64 + quad*16));
      accO1 = MFMA16(ap0, bv0, accO1, 0, 0, 0);
      accO1 = MFMA16(ap1, bv1, accO1, 0, 0, 0);
    }
    {
      short8 bv0 = *(const short8*)(smem + vo + swz(2*16 + ln, quad*16));
      short8 bv1 = *(const short8*)(smem + vo + swz(2*16 + ln, 64 + quad*16));
      accO2 = MFMA16(ap0, bv0, accO2, 0, 0, 0);
      accO2 = MFMA16(ap1, bv1, accO2, 0, 0, 0);
    }
    {
      short8 bv0 = *(const short8*)(smem + vo + swz(3*16 + ln, quad*16));
      short8 bv1 = *(const short8*)(smem + vo + swz(3*16 + ln, 64 + quad*16));
      accO3 = MFMA16(ap0, bv0, accO3, 0, 0, 0);
      accO3 = MFMA16(ap1, bv1, accO3, 0, 0, 0);
    }
    // ---- write next V into the other buffer; rotate K frags ----
    if (kt + 1 < KTPS) {
      int vn = 16384 + ((kt+1) & 1) * 8192;
      *(uint4*)(smem + vn + swz(r0, c0*2)) = vr0;
      *(uint4*)(smem + vn + swz(r1, c1*2)) = vr1;
    }
    ak0 = an0; ak1 = an1;
  }

  // ---- store partials bf16 [c][n] (4 consecutive n at fixed c -> uint2) ----
  size_t pbase = ((size_t)(b*NT + tile)*KS + split)*4096;
  ushort* pp = part + pbase;
  {
    uint2 pk; pk.x = pkbf(accO0[0], accO0[1]); pk.y = pkbf(accO0[2], accO0[3]);
    *(uint2*)&pp[(0*16 + ln)*64 + wv*16 + quad*4] = pk;
  }
  {
    uint2 pk; pk.x = pkbf(accO1[0], accO1[1]); pk.y = pkbf(accO1[2], accO1[3]);
    *(uint2*)&pp[(1*16 + ln)*64 + wv*16 + quad*4] = pk;
  }
  {
    uint2 pk; pk.x = pkbf(accO2[0], accO2[1]); pk.y = pkbf(accO2[2], accO2[3]);
    *(uint2*)&pp[(2*16 + ln)*64 + wv*16 + quad*4] = pk;
  }
  {
    uint2 pk; pk.x = pkbf(accO3[0], accO3[1]); pk.y = pkbf(accO3[2], accO3[3]);
    *(uint2*)&pp[(3*16 + ln)*64 + wv*16 + quad*4] = pk;
  }
  // ---- l: butterfly quads within wave, then cross-wave via LDS ----
  {
    float s = lacc0;
    s += __shfl_xor(s, 16); s += __shfl_xor(s, 32);
    if (quad == 0) lred[wv*64 + 0*16 + ln] = s;
  }
  {
    float s = lacc1;
    s += __shfl_xor(s, 16); s += __shfl_xor(s, 32);
    if (quad == 0) lred[wv*64 + 1*16 + ln] = s;
  }
  {
    float s = lacc2;
    s += __shfl_xor(s, 16); s += __shfl_xor(s, 32);
    if (quad == 0) lred[wv*64 + 2*16 + ln] = s;
  }
  {
    float s = lacc3;
    s += __shfl_xor(s, 16); s += __shfl_xor(s, 32);
    if (quad == 0) lred[wv*64 + 3*16 + ln] = s;
  }
  __syncthreads();
  if (tid < 64) {
    size_t mlb = ((size_t)(b*NT + tile)*KS + split)*64;
    pml[mlb + tid] = (lred[tid] + lred[64 + tid]) + (lred[128 + tid] + lred[192 + tid]);
  }
}

// ---------------------------------------------------------------------------
// attn_reduce: PURE STREAMING (out-conv already folded into V'):
// out[c][n] = sum_s part[s][c][n] / l[n] + outb[c] + x[c][n].
// One block per (b, tile); coalesced uint2 part reads, float4 x/out.
// ---------------------------------------------------------------------------
__global__ __launch_bounds__(256) void attn_reduce(
    const ushort* __restrict__ part, const float* __restrict__ pml,
    const float* __restrict__ x, const float* __restrict__ outb,
    float* __restrict__ out)
{
  __shared__ float linv[64];
  __shared__ float ob[64];

  int tid = threadIdx.x;
  int blk = blockIdx.x;
  int b = blk / NT, tile = blk % NT;
  size_t base = (size_t)(b*NT + tile)*KS;

  if (tid < 64) {
    float l = 0.f;
    #pragma unroll
    for (int s=0;s<KS;++s) l += pml[(base+s)*64 + tid];
    linv[tid] = 1.0f / l;
    ob[tid] = outb[tid];
  }
  __syncthreads();

  // 1024 uint2-chunks (4 n's at fixed c). Wave: q=tid&15 spans a full 128B
  // row, c=tid>>4 -> 4 contiguous rows -> 512B contiguous per instruction.
  #pragma unroll
  for (int j = 0; j < 4; ++j) {
    int idx = j*256 + tid;
    int c = idx >> 4, q = idx & 15;
    float a0=0.f, a1=0.f, a2=0.f, a3=0.f;
    #pragma unroll
    for (int s = 0; s < KS; ++s) {
      uint2 v = *(const uint2*)&part[(base+s)*4096 + (size_t)c*64 + q*4];
      a0 += bu2f((ushort)(v.x & 0xffff)); a1 += bu2f((ushort)(v.x >> 16));
      a2 += bu2f((ushort)(v.y & 0xffff)); a3 += bu2f((ushort)(v.y >> 16));
    }
    int nl = q*4;
    size_t gidx = (size_t)(b*CH + c)*NN + tile*64 + nl;
    float4 xv = *(const float4*)&x[gidx];
    float bc = ob[c];
    float4 o;
    o.x = a0*linv[nl+0] + bc + xv.x;
    o.y = a1*linv[nl+1] + bc + xv.y;
    o.z = a2*linv[nl+2] + bc + xv.z;
    o.w = a3*linv[nl+3] + bc + xv.w;
    *(float4*)&out[gidx] = o;
  }
}

extern "C" void kernel_launch(void* const* d_in, const int* in_sizes, int n_in,
                              void* d_out, int out_size, void* d_ws, size_t ws_size,
                              hipStream_t stream) {
  const float* x    = (const float*)d_in[0];
  const float* q1w  = (const float*)d_in[1];
  const float* q1g  = (const float*)d_in[2];
  const float* q1b  = (const float*)d_in[3];
  const float* q2w  = (const float*)d_in[4];
  const float* q2g  = (const float*)d_in[5];
  const float* q2b  = (const float*)d_in[6];
  const float* q3w  = (const float*)d_in[7];
  const float* q3g  = (const float*)d_in[8];
  const float* q3b  = (const float*)d_in[9];
  const float* khw  = (const float*)d_in[10];
  const float* khb  = (const float*)d_in[11];
  const float* klw  = (const float*)d_in[12];
  const float* klb  = (const float*)d_in[13];
  const float* kfw  = (const float*)d_in[14];
  const float* kfb  = (const float*)d_in[15];
  const float* vbg  = (const float*)d_in[16];
  const float* vbb  = (const float*)d_in[17];
  const float* vw   = (const float*)d_in[18];
  const float* vb   = (const float*)d_in[19];
  const float* outw = (const float*)d_in[20];
  const float* outb = (const float*)d_in[21];

  char*   wsb  = (char*)d_ws;
  float*  biasf= (float*)(wsb + OFF_BIAS);
  bf16*   wh   = (bf16*)(wsb + OFF_WH_B);
  bf16*   lowg = (bf16*)(wsb + OFF_LOW_B);
  bf16*   qgT  = (bf16*)(wsb + OFF_Q_B);
  bf16*   kgT  = (bf16*)(wsb + OFF_K_B);
  bf16*   vgc  = (bf16*)(wsb + OFF_V_B);
  ushort* part = (ushort*)(wsb + OFF_P_B);
  float*  pml  = (float*)(wsb + OFF_ML_B);

  hipLaunchKernelGGL(setup_pool, dim3(16 + BATCH*CH*NN/1024), dim3(256), 0, stream,
                     q1w,q1g,q1b,q2w,q2g,q2b,q3w,q3g,q3b,
                     khw,khb,klw,klb,kfw,kfb,vbg,vbb,vw,vb,outw,
                     x, biasf, wh, lowg);
  hipLaunchKernelGGL(qkv_kernel, dim3(BATCH*NT), dim3(256), 0, stream,
                     x, biasf, wh, lowg, qgT, kgT, vgc);
  hipLaunchKernelGGL(attn_partial, dim3(BATCH*NT*KS), dim3(256), 0, stream,
                     qgT, kgT, vgc, part, pml);
  hipLaunchKernelGGL(attn_reduce, dim3(BATCH*NT), dim3(256), 0, stream,
                     part, pml, x, outb, (float*)d_out);
}